// Round 1
// baseline (24.277 us; speedup 1.0000x reference)
//
#include <hip/hip_runtime.h>

#define NCODE 512

// Kernel 1: single block. Bitonic-sort the 512 (value, original-index) pairs
// ascending by value (ties by index), then propagate the minimum original
// index across equal-value runs (so the tie-break below exactly matches
// jnp.argmin's first-index rule even with duplicate code values).
__global__ __launch_bounds__(NCODE) void sort_codes_kernel(
        const float* __restrict__ emb,
        float* __restrict__ ws_val,
        int* __restrict__ ws_idx) {
    __shared__ float v[NCODE];
    __shared__ int ix[NCODE];
    const int t = threadIdx.x;
    v[t] = emb[t];
    ix[t] = t;
    __syncthreads();
    for (int k = 2; k <= NCODE; k <<= 1) {
        for (int j = k >> 1; j > 0; j >>= 1) {
            const int partner = t ^ j;
            if (partner > t) {
                const bool up = ((t & k) == 0);
                const float a = v[t], b = v[partner];
                const int ia = ix[t], ib = ix[partner];
                const bool bad = up ? ((a > b) || (a == b && ia > ib))
                                    : ((a < b) || (a == b && ia < ib));
                if (bad) {
                    v[t] = b; v[partner] = a;
                    ix[t] = ib; ix[partner] = ia;
                }
            }
            __syncthreads();
        }
    }
    // min original index over each run of equal values (runs are ~1 long for
    // random normals; loop is effectively free).
    const float myv = v[t];
    int p = t;
    while (p > 0 && v[p - 1] == myv) --p;
    const int fixed = ix[p];
    __syncthreads();   // all reads of ix[] complete before writes
    ix[t] = fixed;
    __syncthreads();
    ws_val[t] = v[t];
    ws_idx[t] = ix[t];
}

// Kernel 2: per f32 element, branchless 9-step binary search (last index with
// s_val[pos] <= x; Shar's algorithm, no bounds checks needed for pow2 size),
// then compare the two neighbor candidates with exact-f32 distances and the
// original-index tie-break.
__global__ __launch_bounds__(256) void quantize_kernel(
        const float4* __restrict__ h4,
        const float* __restrict__ ws_val,
        const int* __restrict__ ws_idx,
        float4* __restrict__ out4, int n4) {
    __shared__ float s_val[NCODE];
    __shared__ int s_idx[NCODE];
    const int t = threadIdx.x;
    s_val[t]       = ws_val[t];
    s_val[t + 256] = ws_val[t + 256];
    s_idx[t]       = ws_idx[t];
    s_idx[t + 256] = ws_idx[t + 256];
    __syncthreads();

    const int gid = blockIdx.x * 256 + t;
    if (gid >= n4) return;

    const float4 x4 = h4[gid];
    float xs[4] = {x4.x, x4.y, x4.z, x4.w};
    float r[4];
#pragma unroll
    for (int e = 0; e < 4; ++e) {
        const float x = xs[e];
        int pos = 0;
#pragma unroll
        for (int step = NCODE / 2; step >= 1; step >>= 1) {
            const int np = pos + step;            // never exceeds NCODE-1
            pos = (s_val[np] <= x) ? np : pos;
        }
        const int hi = (pos + 1 < NCODE) ? pos + 1 : NCODE - 1;
        const float vl = s_val[pos], vh = s_val[hi];
        const float dl = fabsf(x - vl);
        const float dh = fabsf(x - vh);
        const bool pick_hi = (dh < dl) || ((dh == dl) && (s_idx[hi] < s_idx[pos]));
        r[e] = pick_hi ? vh : vl;
    }
    out4[gid] = make_float4(r[0], r[1], r[2], r[3]);
}

extern "C" void kernel_launch(void* const* d_in, const int* in_sizes, int n_in,
                              void* d_out, int out_size, void* d_ws, size_t ws_size,
                              hipStream_t stream) {
    const float* h   = (const float*)d_in[0];
    const float* emb = (const float*)d_in[1];
    float* out = (float*)d_out;

    float* ws_val = (float*)d_ws;
    int*   ws_idx = (int*)((char*)d_ws + NCODE * sizeof(float));

    sort_codes_kernel<<<1, NCODE, 0, stream>>>(emb, ws_val, ws_idx);

    const int n = in_sizes[0];
    const int n4 = n / 4;
    const int blocks = (n4 + 255) / 256;
    quantize_kernel<<<blocks, 256, 0, stream>>>(
        (const float4*)h, ws_val, ws_idx, (float4*)out, n4);
}

// Round 2
// 17.529 us; speedup vs baseline: 1.3850x; 1.3850x over previous
//
#include <hip/hip_runtime.h>

#define NCODE 512
#define NB 2048          // LUT buckets
#define NTHR 512         // threads per block (== NCODE)

struct U64x2 { unsigned long long x, y; };

__global__ __launch_bounds__(NTHR) void quantize_fused(
        const float* __restrict__ emb,
        const float4* __restrict__ h4,
        float4* __restrict__ out4,
        int n4) {
    __shared__ __align__(16) unsigned long long s_keys[NCODE];
    __shared__ float s_val[NCODE + 16];           // +16 pad of +INF
    __shared__ unsigned short s_idx[NCODE + 16];
    __shared__ unsigned int s_hist[NB];
    __shared__ unsigned int s_tsum[NTHR];
    __shared__ unsigned short s_start[NB];
    __shared__ float s_red[16];                   // 8 wave-mins + 8 wave-maxs
    __shared__ float s_vmin_sh, s_invw_sh;
    __shared__ int s_flag;

    const int t = threadIdx.x;
    const float v = emb[t];                       // NTHR == NCODE

    // ---- block min/max of codes (wave shfl reduce, then 8-way) ----
    float mn = v, mx = v;
    #pragma unroll
    for (int o = 32; o >= 1; o >>= 1) {
        mn = fminf(mn, __shfl_xor(mn, o));
        mx = fmaxf(mx, __shfl_xor(mx, o));
    }
    if ((t & 63) == 0) { s_red[t >> 6] = mn; s_red[8 + (t >> 6)] = mx; }
    if (t == 0) s_flag = 0;

    // ---- sortable 64-bit key: (monotone f32 bits) << 16 | original idx ----
    unsigned int fb = __float_as_uint(v);
    unsigned int u = fb ^ ((fb & 0x80000000u) ? 0xFFFFFFFFu : 0x80000000u);
    s_keys[t] = (((unsigned long long)u) << 16) | (unsigned int)t;

    // zero histogram
    #pragma unroll
    for (int k = 0; k < NB / NTHR; ++k) s_hist[t + k * NTHR] = 0;

    __syncthreads();

    if (t == 0) {
        float m0 = s_red[0], M0 = s_red[8];
        #pragma unroll
        for (int i = 1; i < 8; ++i) { m0 = fminf(m0, s_red[i]); M0 = fmaxf(M0, s_red[8 + i]); }
        float range = M0 - m0;
        s_vmin_sh = m0;
        s_invw_sh = (range > 0.0f) ? ((float)NB / range) : 0.0f;  // degenerate -> all bucket 0 -> flag -> fallback
    }

    // ---- rank sort: rank = # keys < mine (broadcast b128 reads, no conflicts) ----
    const unsigned long long myk = s_keys[t];
    int rank = 0;
    const U64x2* kp = (const U64x2*)s_keys;
    #pragma unroll 8
    for (int j = 0; j < NCODE / 2; ++j) {
        U64x2 kk = kp[j];
        rank += (kk.x < myk) ? 1 : 0;
        rank += (kk.y < myk) ? 1 : 0;
    }
    s_val[rank] = v;
    s_idx[rank] = (unsigned short)t;
    if (t < 16) { s_val[NCODE + t] = __builtin_huge_valf(); s_idx[NCODE + t] = 0; }
    __syncthreads();

    // ---- propagate min original index across equal-value runs (tie semantics) ----
    {
        float myv = s_val[t];
        int p = t;
        while (p > 0 && s_val[p - 1] == myv) --p;   // runs are ~1 for random codes
        unsigned short fixedIdx = s_idx[p];
        __syncthreads();
        s_idx[t] = fixedIdx;
    }

    // ---- histogram of code buckets (monotone bucket map) ----
    const float vmin = s_vmin_sh;
    const float invw = s_invw_sh;
    {
        float bf = fminf(fmaxf((v - vmin) * invw, 0.0f), (float)(NB - 1));
        atomicAdd(&s_hist[(int)bf], 1u);
    }
    __syncthreads();

    // ---- exclusive prefix scan over 2048 buckets (4 per thread + Hillis-Steele) ----
    unsigned int h0 = s_hist[4 * t], h1 = s_hist[4 * t + 1],
                 h2 = s_hist[4 * t + 2], h3 = s_hist[4 * t + 3];
    unsigned int s = h0 + h1 + h2 + h3;
    s_tsum[t] = s;
    __syncthreads();
    for (int off = 1; off < NTHR; off <<= 1) {
        unsigned int add = (t >= off) ? s_tsum[t - off] : 0u;
        __syncthreads();
        s_tsum[t] += add;
        __syncthreads();
    }
    {
        unsigned int excl = s_tsum[t] - s;
        unsigned int c[5] = {excl, excl + h0, excl + h0 + h1, excl + h0 + h1 + h2, excl + s};
        int viol = 0;
        #pragma unroll
        for (int k = 0; k < 4; ++k) {
            int lo = (int)c[k] - 1; if (lo < 0) lo = 0;
            s_start[4 * t + k] = (unsigned short)lo;
            // answer for bucket b lies in [lo, c[b+1]-1]; 4 steps cover a span of 15
            viol |= (((int)c[k + 1] - 1 - lo) > 15) ? 1 : 0;
        }
        if (viol) atomicOr(&s_flag, 1);
    }
    __syncthreads();

    const bool fallback = (s_flag != 0);

    // ---- grid-stride quantize: LUT seed + 4 branchless refine steps ----
    const int gsize = gridDim.x * NTHR;
    for (int i = blockIdx.x * NTHR + t; i < n4; i += gsize) {
        float4 x4 = h4[i];
        float xs[4] = {x4.x, x4.y, x4.z, x4.w};
        float r[4];
        if (!fallback) {
            #pragma unroll
            for (int e = 0; e < 4; ++e) {
                float x = xs[e];
                float bfx = fminf(fmaxf((x - vmin) * invw, 0.0f), (float)(NB - 1));
                int pos = s_start[(int)bfx];
                float vc = s_val[pos];
                #pragma unroll
                for (int st = 8; st >= 1; st >>= 1) {
                    int np = pos + st;
                    float vn = s_val[np];          // pad makes np<=527 safe (+INF)
                    bool take = (vn <= x);
                    pos = take ? np : pos;
                    vc = take ? vn : vc;
                }
                int hi = pos + 1;
                float vh = s_val[hi];
                float dl = fabsf(x - vc), dh = fabsf(x - vh);
                bool ph = dh < dl;
                if (dh == dl) ph = (s_idx[hi] < s_idx[pos]);   // exact midpoint: original-index tie-break (rare)
                r[e] = ph ? vh : vc;
            }
        } else {
            #pragma unroll
            for (int e = 0; e < 4; ++e) {
                float x = xs[e];
                int pos = 0;
                float vc = s_val[0];
                #pragma unroll
                for (int st = NCODE / 2; st >= 1; st >>= 1) {
                    int np = pos + st;
                    float vn = s_val[np];
                    bool take = (vn <= x);
                    pos = take ? np : pos;
                    vc = take ? vn : vc;
                }
                int hi = pos + 1;
                float vh = s_val[hi];
                float dl = fabsf(x - vc), dh = fabsf(x - vh);
                bool ph = dh < dl;
                if (dh == dl) ph = (s_idx[hi] < s_idx[pos]);
                r[e] = ph ? vh : vc;
            }
        }
        out4[i] = make_float4(r[0], r[1], r[2], r[3]);
    }
}

extern "C" void kernel_launch(void* const* d_in, const int* in_sizes, int n_in,
                              void* d_out, int out_size, void* d_ws, size_t ws_size,
                              hipStream_t stream) {
    const float* h   = (const float*)d_in[0];
    const float* emb = (const float*)d_in[1];
    float* out = (float*)d_out;

    const int n = in_sizes[0];
    const int n4 = n / 4;
    const int blocks = 256;   // 1 per CU: redundant per-block codebook build, all parallel
    quantize_fused<<<blocks, NTHR, 0, stream>>>(
        emb, (const float4*)h, (float4*)out, n4);
}

// Round 3
// 12.316 us; speedup vs baseline: 1.9713x; 1.4233x over previous
//
#include <hip/hip_runtime.h>

#define NCODE 512
#define NB 2048          // LUT buckets (monotone in value)
#define NTHR 512

__global__ __launch_bounds__(NTHR) void quantize_fused(
        const float* __restrict__ emb,
        const float4* __restrict__ h4,
        float4* __restrict__ out4,
        int n4) {
    __shared__ __align__(16) unsigned long long s_tmp[NCODE];   // bucket-grouped keys
    __shared__ float s_val[NCODE + 16];            // sorted codes, +16 pad of +INF
    __shared__ unsigned short s_idx[NCODE + 16];   // run-min original index
    __shared__ unsigned int s_excl[NB + 1];        // counts -> exclusive starts
    __shared__ unsigned short s_start[NB];         // LUT: clamp(excl-1,0)
    __shared__ float s_red[16];
    __shared__ unsigned int s_wt[8];
    __shared__ int s_flag;

    const int t = threadIdx.x;
    const int lane = t & 63;
    const int wv = t >> 6;

    const float v = emb[t];                        // NTHR == NCODE

    // ---- block min/max of codes (shfl reduce, partials to LDS) ----
    float mn = v, mx = v;
    #pragma unroll
    for (int o = 32; o >= 1; o >>= 1) {
        mn = fminf(mn, __shfl_xor(mn, o));
        mx = fmaxf(mx, __shfl_xor(mx, o));
    }
    if (lane == 0) { s_red[wv] = mn; s_red[8 + wv] = mx; }
    if (t == 0) s_flag = 0;
    // zero histogram (4 entries/thread) + boundary
    s_excl[t] = 0; s_excl[t + 512] = 0; s_excl[t + 1024] = 0; s_excl[t + 1536] = 0;
    if (t == 0) s_excl[NB] = 0;
    __syncthreads();                               // B1

    // every thread redundantly reduces the 8 partials (broadcast reads, no barrier)
    float vmin, invw;
    {
        float m0 = s_red[0], M0 = s_red[8];
        #pragma unroll
        for (int i = 1; i < 8; ++i) { m0 = fminf(m0, s_red[i]); M0 = fmaxf(M0, s_red[8 + i]); }
        vmin = m0;
        float range = M0 - m0;
        invw = (range > 0.0f) ? ((float)NB / range) : 0.0f;  // degenerate -> viol -> fallback
    }

    // ---- sortable key: (monotone f32 bits) << 16 | original idx ----
    unsigned int fb = __float_as_uint(v);
    unsigned int u = fb ^ ((fb & 0x80000000u) ? 0xFFFFFFFFu : 0x80000000u);
    const unsigned long long myk = (((unsigned long long)u) << 16) | (unsigned int)t;

    int b;
    {
        float bf = fminf(fmaxf((v - vmin) * invw, 0.0f), (float)(NB - 1));
        b = (int)bf;
    }
    const unsigned int slot = atomicAdd(&s_excl[b], 1u);   // arrival order in bucket
    __syncthreads();                               // B2: histogram final

    // ---- exclusive scan over 2048 buckets: 4/thread + wave shfl scan ----
    unsigned int h0 = s_excl[4 * t], h1 = s_excl[4 * t + 1],
                 h2 = s_excl[4 * t + 2], h3 = s_excl[4 * t + 3];
    unsigned int s = h0 + h1 + h2 + h3;
    unsigned int incl = s;
    #pragma unroll
    for (int o = 1; o < 64; o <<= 1) {
        unsigned int w = __shfl_up(incl, o);
        if (lane >= o) incl += w;
    }
    if (lane == 63) s_wt[wv] = incl;
    __syncthreads();                               // B3
    unsigned int base = 0;
    #pragma unroll
    for (int i = 0; i < 8; ++i) base += (i < wv) ? s_wt[i] : 0u;
    const unsigned int e0 = base + incl - s;       // exclusive start of bucket 4t
    const unsigned int c0 = e0, c1 = c0 + h0, c2 = c1 + h1, c3 = c2 + h2, c4 = c3 + h3;
    {
        int viol = 0, lo;
        lo = (int)c0 - 1; if (lo < 0) lo = 0; s_start[4 * t + 0] = (unsigned short)lo; viol |= ((int)c1 - 1 - lo) > 15;
        lo = (int)c1 - 1; if (lo < 0) lo = 0; s_start[4 * t + 1] = (unsigned short)lo; viol |= ((int)c2 - 1 - lo) > 15;
        lo = (int)c2 - 1; if (lo < 0) lo = 0; s_start[4 * t + 2] = (unsigned short)lo; viol |= ((int)c3 - 1 - lo) > 15;
        lo = (int)c3 - 1; if (lo < 0) lo = 0; s_start[4 * t + 3] = (unsigned short)lo; viol |= ((int)c4 - 1 - lo) > 15;
        if (viol) atomicOr(&s_flag, 1);
    }
    // overwrite own counts with exclusive starts
    s_excl[4 * t] = c0; s_excl[4 * t + 1] = c1; s_excl[4 * t + 2] = c2; s_excl[4 * t + 3] = c3;
    if (t == NTHR - 1) s_excl[NB] = c4;            // == NCODE
    __syncthreads();                               // B4: excl[] ready

    // ---- scatter into bucket-grouped order, then exact within-bucket rank ----
    const unsigned int lo_b = s_excl[b];
    const unsigned int hi_b = s_excl[b + 1];
    s_tmp[lo_b + slot] = myk;
    __syncthreads();                               // B5
    {
        int r = 0;
        unsigned int minEq = (unsigned int)t;
        for (unsigned int j = lo_b; j < hi_b; ++j) {   // span <= ~15 (viol-checked)
            unsigned long long k2 = s_tmp[j];
            r += (k2 < myk) ? 1 : 0;
            unsigned int u2 = (unsigned int)(k2 >> 16);
            unsigned int fb2 = u2 ^ ((u2 & 0x80000000u) ? 0x80000000u : 0xFFFFFFFFu);
            float v2 = __uint_as_float(fb2);
            if (v2 == v) {                          // float eq: handles +-0, dups
                unsigned int i2 = (unsigned int)(k2 & 0xFFFFull);
                minEq = (i2 < minEq) ? i2 : minEq;
            }
        }
        const int pos = (int)lo_b + r;
        s_val[pos] = v;
        s_idx[pos] = (unsigned short)minEq;        // run-min original index
    }
    if (t < 16) { s_val[NCODE + t] = __builtin_huge_valf(); s_idx[NCODE + t] = 0; }
    __syncthreads();                               // B6: structure ready

    const bool fallback = (s_flag != 0);

    // ---- quantize: LUT seed + 4 branchless refine steps ----
    const int gsize = gridDim.x * NTHR;
    for (int i = blockIdx.x * NTHR + t; i < n4; i += gsize) {
        float4 x4 = h4[i];
        float xs[4] = {x4.x, x4.y, x4.z, x4.w};
        float r[4];
        if (!fallback) {
            #pragma unroll
            for (int e = 0; e < 4; ++e) {
                float x = xs[e];
                float bfx = fminf(fmaxf((x - vmin) * invw, 0.0f), (float)(NB - 1));
                int pos = s_start[(int)bfx];
                float vc = s_val[pos];
                #pragma unroll
                for (int st = 8; st >= 1; st >>= 1) {
                    int np = pos + st;
                    float vn = s_val[np];          // pad makes np<=526 safe (+INF)
                    bool take = (vn <= x);
                    pos = take ? np : pos;
                    vc = take ? vn : vc;
                }
                int hi = pos + 1;
                float vh = s_val[hi];
                float dl = fabsf(x - vc), dh = fabsf(x - vh);
                bool ph = dh < dl;
                if (dh == dl) ph = (s_idx[hi] < s_idx[pos]);   // exact midpoint: rare
                r[e] = ph ? vh : vc;
            }
        } else {
            #pragma unroll
            for (int e = 0; e < 4; ++e) {
                float x = xs[e];
                int pos = 0;
                float vc = s_val[0];
                #pragma unroll
                for (int st = NCODE / 2; st >= 1; st >>= 1) {
                    int np = pos + st;
                    float vn = s_val[np];
                    bool take = (vn <= x);
                    pos = take ? np : pos;
                    vc = take ? vn : vc;
                }
                int hi = pos + 1;
                float vh = s_val[hi];
                float dl = fabsf(x - vc), dh = fabsf(x - vh);
                bool ph = dh < dl;
                if (dh == dl) ph = (s_idx[hi] < s_idx[pos]);
                r[e] = ph ? vh : vc;
            }
        }
        out4[i] = make_float4(r[0], r[1], r[2], r[3]);
    }
}

extern "C" void kernel_launch(void* const* d_in, const int* in_sizes, int n_in,
                              void* d_out, int out_size, void* d_ws, size_t ws_size,
                              hipStream_t stream) {
    const float* h   = (const float*)d_in[0];
    const float* emb = (const float*)d_in[1];
    float* out = (float*)d_out;

    const int n = in_sizes[0];
    const int n4 = n / 4;                  // 262144
    const int blocks = 512;                // 2 blocks/CU, 1 float4/thread
    quantize_fused<<<blocks, NTHR, 0, stream>>>(
        emb, (const float4*)h, (float4*)out, n4);
}

// Round 4
// 11.736 us; speedup vs baseline: 2.0686x; 1.0494x over previous
//
#include <hip/hip_runtime.h>

#define NCODE 512
#define NB    2048
#define NTHR  1024
#define FINF  __builtin_huge_valf()

// monotone f32 <-> u32 order-preserving map
__device__ __forceinline__ unsigned int fmap(float f) {
    unsigned int b = __float_as_uint(f);
    return b ^ ((b & 0x80000000u) ? 0xFFFFFFFFu : 0x80000000u);
}
__device__ __forceinline__ float funmap(unsigned int u) {
    unsigned int b = (u & 0x80000000u) ? (u ^ 0x80000000u) : ~u;
    return __uint_as_float(b);
}
__device__ __forceinline__ int bucket_of(float x, float vmin, float invw) {
    float bf = fminf(fmaxf((x - vmin) * invw, 0.0f), (float)(NB - 1));
    return (int)bf;
}
// exact reference predicate: prefer upper code vh over lower vl at point x
// (x in [vl,vh]; dl,dh match jnp.abs f32 rounding; tie -> smaller orig index)
__device__ __forceinline__ bool pick_hi(float x, float vl, float vh,
                                        unsigned int il, unsigned int ih) {
    float dl = x - vl;
    float dh = vh - x;
    return (dh < dl) || ((dh == dl) && (ih < il));
}

__global__ __launch_bounds__(NTHR) void quantize_fused(
        const float* __restrict__ emb,
        const float4* __restrict__ h4,
        float4* __restrict__ out4,
        int n4) {
    __shared__ float4 s_lut[NB];                 // (thrA,thrB,thrC, bits=j|flag)
    __shared__ unsigned int s_excl[NB + 1];
    __shared__ unsigned long long s_tmp[NCODE];
    __shared__ float s_val[NCODE + 16];          // sorted codes (+pad)
    __shared__ float s_thr[NCODE];               // 511 sorted thresholds + INF
    __shared__ unsigned short s_idx[NCODE];      // run-min original index
    __shared__ float s_red[32];
    __shared__ unsigned int s_wt[16];

    const int t = threadIdx.x;
    const int lane = t & 63;
    const int wv = t >> 6;

    const int gid = blockIdx.x * NTHR + t;
    const bool live = (gid < n4);
    float4 x4 = make_float4(0.f, 0.f, 0.f, 0.f);
    if (live) x4 = h4[gid];                      // prefetch: latency hides under setup

    s_excl[t] = 0; s_excl[t + NTHR] = 0;
    if (t == 0) s_excl[NB] = 0;

    float v = 0.0f;
    if (t < NCODE) {
        v = emb[t];
        float mn = v, mx = v;
        #pragma unroll
        for (int o = 32; o >= 1; o >>= 1) {
            mn = fminf(mn, __shfl_xor(mn, o));
            mx = fmaxf(mx, __shfl_xor(mx, o));
        }
        if (lane == 0) { s_red[wv] = mn; s_red[16 + wv] = mx; }
    }
    __syncthreads();                                   // B1

    float vmin, invw;
    {
        float m0 = s_red[0], M0 = s_red[16];
        #pragma unroll
        for (int i = 1; i < 8; ++i) { m0 = fminf(m0, s_red[i]); M0 = fmaxf(M0, s_red[16 + i]); }
        vmin = m0;
        float range = M0 - m0;
        invw = (range > 0.0f) ? ((float)NB / range) : 0.0f;  // degenerate -> all bucket0 -> flagged -> exact fallback
    }

    // ---- code histogram ----
    int b = 0; unsigned int slot = 0;
    unsigned long long myk = 0;
    if (t < NCODE) {
        myk = (((unsigned long long)fmap(v)) << 16) | (unsigned int)t;
        b = bucket_of(v, vmin, invw);
        slot = atomicAdd(&s_excl[b], 1u);
    }
    __syncthreads();                                   // B2

    // ---- scan #1 over 2048 buckets (2/thread + wave shfl scan) ----
    {
        unsigned int h0 = s_excl[2 * t], h1 = s_excl[2 * t + 1];
        unsigned int s = h0 + h1, incl = s;
        #pragma unroll
        for (int o = 1; o < 64; o <<= 1) {
            unsigned int w = __shfl_up(incl, o);
            if (lane >= o) incl += w;
        }
        if (lane == 63) s_wt[wv] = incl;
        __syncthreads();                               // B3
        unsigned int base = 0;
        #pragma unroll
        for (int i = 0; i < 16; ++i) base += (i < wv) ? s_wt[i] : 0u;
        unsigned int c0 = base + incl - s;
        s_excl[2 * t] = c0; s_excl[2 * t + 1] = c0 + h0;
        if (t == NTHR - 1) s_excl[NB] = c0 + h0 + h1;
    }
    __syncthreads();                                   // B4

    // ---- scatter keys into bucket groups ----
    unsigned int lo_b = 0, hi_b = 0;
    if (t < NCODE) {
        lo_b = s_excl[b]; hi_b = s_excl[b + 1];
        s_tmp[lo_b + slot] = myk;
    }
    __syncthreads();                                   // B5

    // ---- exact within-bucket rank + run-min original index ----
    if (t < NCODE) {
        int r = 0; unsigned int minEq = (unsigned int)t;
        for (unsigned int j = lo_b; j < hi_b; ++j) {
            unsigned long long k2 = s_tmp[j];
            r += (k2 < myk) ? 1 : 0;
            float v2 = funmap((unsigned int)(k2 >> 16));
            if (v2 == v) {
                unsigned int i2 = (unsigned int)(k2 & 0xFFFFull);
                minEq = (i2 < minEq) ? i2 : minEq;
            }
        }
        int pos = (int)lo_b + r;
        s_val[pos] = v;
        s_idx[pos] = (unsigned short)minEq;
    } else if (t < NCODE + 16) {
        s_val[t] = FINF;
    }
    __syncthreads();                                   // B6

    // ---- thresholds (t<511) in parallel with excl re-zero (t>=512) ----
    float thrReg = FINF;
    if (t < NCODE - 1) {
        float vl = s_val[t], vh = s_val[t + 1];
        unsigned int il = s_idx[t], ih = s_idx[t + 1];
        if (vl == vh) {
            thrReg = vl;                                // same value: any consistent thr
        } else {
            unsigned int ulo = fmap(vl), uhi = fmap(vh);
            unsigned int um = fmap(0.5f * (vl + vh));   // in [ulo,uhi] by rounding monotonicity
            unsigned int a  = (um - ulo >= 8u) ? um - 8u : ulo;
            unsigned int b2 = (uhi - um >= 8u) ? um + 8u : uhi;
            if (!pick_hi(funmap(a),  vl, vh, il, ih)) ulo = a;   // tighten window if valid
            if ( pick_hi(funmap(b2), vl, vh, il, ih)) uhi = b2;
            while (uhi - ulo > 1u) {                    // <=4 iters windowed, <=32 worst
                unsigned int mid = ulo + ((uhi - ulo) >> 1);
                if (pick_hi(funmap(mid), vl, vh, il, ih)) uhi = mid; else ulo = mid;
            }
            thrReg = funmap(uhi);                       // smallest f32 x preferring vh
        }
        s_thr[t] = thrReg;
    } else if (t == NCODE - 1) {
        s_thr[t] = FINF;
    } else {
        int t2 = t - NCODE;                             // 512 threads re-zero 2049 entries
        s_excl[t2] = 0; s_excl[t2 + 512] = 0; s_excl[t2 + 1024] = 0; s_excl[t2 + 1536] = 0;
        if (t2 == 0) s_excl[NB] = 0;
    }
    __syncthreads();                                   // B7

    // ---- threshold histogram ----
    if (t < NCODE - 1) atomicAdd(&s_excl[bucket_of(thrReg, vmin, invw)], 1u);
    __syncthreads();                                   // B8

    // ---- scan #2 (identical) ----
    {
        unsigned int h0 = s_excl[2 * t], h1 = s_excl[2 * t + 1];
        unsigned int s = h0 + h1, incl = s;
        #pragma unroll
        for (int o = 1; o < 64; o <<= 1) {
            unsigned int w = __shfl_up(incl, o);
            if (lane >= o) incl += w;
        }
        if (lane == 63) s_wt[wv] = incl;
        __syncthreads();                               // B9
        unsigned int base = 0;
        #pragma unroll
        for (int i = 0; i < 16; ++i) base += (i < wv) ? s_wt[i] : 0u;
        unsigned int c0 = base + incl - s;
        s_excl[2 * t] = c0; s_excl[2 * t + 1] = c0 + h0;
        if (t == NTHR - 1) s_excl[NB] = c0 + h0 + h1;
    }
    __syncthreads();                                   // B10

    // ---- build LUT: up to 3 thresholds + base index per bucket, one float4 ----
    #pragma unroll
    for (int k = 0; k < 2; ++k) {
        int bb = 2 * t + k;
        unsigned int j = s_excl[bb];
        unsigned int cnt = s_excl[bb + 1] - j;
        float4 w;
        if (cnt <= 3u) {
            w.x = (cnt >= 1u) ? s_thr[j]     : FINF;
            w.y = (cnt >= 2u) ? s_thr[j + 1] : FINF;
            w.z = (cnt >= 3u) ? s_thr[j + 2] : FINF;
            w.w = __uint_as_float(j);
        } else {
            w.x = FINF; w.y = FINF; w.z = FINF;
            w.w = __uint_as_float(j | 0x80000000u);     // rare: exact full search
        }
        s_lut[bb] = w;
    }
    __syncthreads();                                   // B11

    // ---- quantize: 1 b128 + 3 cmps (+1 b32) per element ----
    if (live) {
        float xs[4] = {x4.x, x4.y, x4.z, x4.w};
        float rr[4];
        #pragma unroll
        for (int e = 0; e < 4; ++e) {
            float x = xs[e];
            float4 L = s_lut[bucket_of(x, vmin, invw)];
            unsigned int bits = __float_as_uint(L.w);
            int r = (int)(bits & 0xFFFFu);
            r += (x >= L.x) ? 1 : 0;
            r += (x >= L.y) ? 1 : 0;
            r += (x >= L.z) ? 1 : 0;
            if (bits & 0x80000000u) {                  // flagged bucket: exact count
                r = 0;
                #pragma unroll
                for (int st = 256; st >= 1; st >>= 1)
                    r += (s_thr[r + st - 1] <= x) ? st : 0;
            }
            rr[e] = s_val[r];
        }
        out4[gid] = make_float4(rr[0], rr[1], rr[2], rr[3]);
    }
}

extern "C" void kernel_launch(void* const* d_in, const int* in_sizes, int n_in,
                              void* d_out, int out_size, void* d_ws, size_t ws_size,
                              hipStream_t stream) {
    const float* h   = (const float*)d_in[0];
    const float* emb = (const float*)d_in[1];
    float* out = (float*)d_out;

    const int n = in_sizes[0];
    const int n4 = n / 4;                        // 262144
    const int blocks = (n4 + NTHR - 1) / NTHR;   // 256: one block per CU
    quantize_fused<<<blocks, NTHR, 0, stream>>>(
        emb, (const float4*)h, (float4*)out, n4);
}